// Round 9
// baseline (37.131 us; speedup 1.0000x reference)
//
#include <hip/hip_runtime.h>
#include <hip/hip_bf16.h>
#include <math.h>

#define B_   4
#define C_   64
#define N_   4096
#define L2E  1.4426950408889634f

typedef __attribute__((ext_vector_type(8)))  short bf16x8;
typedef __attribute__((ext_vector_type(4)))  float f32x4;
typedef __attribute__((ext_vector_type(16))) float f32x16;
typedef __attribute__((ext_vector_type(4)))  uint  uint4v;

#define MFMA16(a,b,c) __builtin_amdgcn_mfma_f32_16x16x32_bf16(a,b,c,0,0,0)
#define MFMA32(a,b,c) __builtin_amdgcn_mfma_f32_32x32x16_bf16(a,b,c,0,0,0)

static __device__ inline ushort f2bf(float f) {
    __hip_bfloat16 h = __float2bfloat16(f);
    return *reinterpret_cast<ushort*>(&h);
}
static __device__ inline uint packbf(float a, float b) {
    return (uint)f2bf(a) | ((uint)f2bf(b) << 16);
}
static __device__ inline uint cvtpk(float lo, float hi) {
    uint r;
    asm("v_cvt_pk_bf16_f32 %0, %1, %2" : "=v"(r) : "v"(lo), "v"(hi));
    return r;
}
static __device__ inline void plswap(uint &a, uint &b) {
    asm("v_permlane32_swap_b32 %0, %1" : "+v"(a), "+v"(b));
}
// pairwise max/sum trees over a 16-vec (depth 4, exposes ILP)
static __device__ inline float tmax16(const f32x16 &s) {
    float a0 = fmaxf(s[0], s[1]),  a1 = fmaxf(s[2], s[3]);
    float a2 = fmaxf(s[4], s[5]),  a3 = fmaxf(s[6], s[7]);
    float a4 = fmaxf(s[8], s[9]),  a5 = fmaxf(s[10], s[11]);
    float a6 = fmaxf(s[12], s[13]), a7 = fmaxf(s[14], s[15]);
    a0 = fmaxf(a0, a1); a2 = fmaxf(a2, a3); a4 = fmaxf(a4, a5); a6 = fmaxf(a6, a7);
    return fmaxf(fmaxf(a0, a2), fmaxf(a4, a6));
}
static __device__ inline float tsum16(const f32x16 &s) {
    float a0 = s[0] + s[1],  a1 = s[2] + s[3];
    float a2 = s[4] + s[5],  a3 = s[6] + s[7];
    float a4 = s[8] + s[9],  a5 = s[10] + s[11];
    float a6 = s[12] + s[13], a7 = s[14] + s[15];
    a0 += a1; a2 += a3; a4 += a5; a6 += a7;
    return (a0 + a2) + (a4 + a6);
}

// ---------------- QKV projection: LDS-staged coalesced loads + MFMA --------
// Q,K: [B][N][16] bf16.  V: fragment-major VT[B][N/16][64 c][16 j] bf16.
// x/xrgb tiles staged via float4 (full coalescing) into pad-68 LDS rows;
// fragments then read as aligned f32x4 (2-way max bank aliasing = free).
__global__ __launch_bounds__(256) void qkv_mfma(
    const float* __restrict__ x, const float* __restrict__ xrgb,
    const float* __restrict__ Wq, const float* __restrict__ bq,
    const float* __restrict__ Wk, const float* __restrict__ bk,
    const float* __restrict__ Wv, const float* __restrict__ bv,
    ushort* __restrict__ Qo, ushort* __restrict__ Ko, ushort* __restrict__ Vo)
{
    __shared__ float XL[32][68];     // [px][c] x tile, 8704B
    __shared__ float RL[32][68];     // xrgb tile
    __shared__ float BLs[96];
    __shared__ float OP[2][96][33];  // per-cw partials

    const int t = threadIdx.x, b = blockIdx.y, n0 = blockIdx.x * 32;
    const int w = t >> 6, lane = t & 63, li = lane & 15, g = lane >> 4;
    const int pw = w & 1, cw = w >> 1;

    // coalesced stage: idx -> c = idx>>3, px-quad q = idx&7
    #pragma unroll
    for (int l = 0; l < 2; ++l) {
        const int idx = t + l * 256;
        const int c = idx >> 3, q = idx & 7;
        const float4 xv = *(const float4*)(x    + ((size_t)b * C_ + c) * N_ + n0 + q * 4);
        const float4 rv = *(const float4*)(xrgb + ((size_t)b * C_ + c) * N_ + n0 + q * 4);
        XL[q * 4 + 0][c] = xv.x; XL[q * 4 + 1][c] = xv.y;
        XL[q * 4 + 2][c] = xv.z; XL[q * 4 + 3][c] = xv.w;
        RL[q * 4 + 0][c] = rv.x; RL[q * 4 + 1][c] = rv.y;
        RL[q * 4 + 2][c] = rv.z; RL[q * 4 + 3][c] = rv.w;
    }

    // W fragments direct from global (issued before the barrier for overlap)
    const int c0 = cw * 32 + g * 8;
    float wf[6][8];
    #pragma unroll
    for (int ot = 0; ot < 6; ++ot) {
        const float* wsrc;
        if (ot == 0)      wsrc = Wq + li * 64 + c0;
        else if (ot == 1) wsrc = Wk + li * 64 + c0;
        else              wsrc = Wv + ((ot - 2) * 16 + li) * 64 + c0;
        const float4 a = *(const float4*)(wsrc);
        const float4 c4 = *(const float4*)(wsrc + 4);
        wf[ot][0] = a.x;  wf[ot][1] = a.y;  wf[ot][2] = a.z;  wf[ot][3] = a.w;
        wf[ot][4] = c4.x; wf[ot][5] = c4.y; wf[ot][6] = c4.z; wf[ot][7] = c4.w;
    }
    if (t < 96)
        BLs[t] = (t < 16) ? bq[t] * L2E : (t < 32 ? bk[t - 16] : bv[t - 32]);
    __syncthreads();

    // B-fragments from LDS (aligned f32x4, row pad 68)
    const int px = pw * 16 + li;
    const f32x4 x0 = *(const f32x4*)&XL[px][c0];
    const f32x4 x1 = *(const f32x4*)&XL[px][c0 + 4];
    const f32x4 r0 = *(const f32x4*)&RL[px][c0];
    const f32x4 r1 = *(const f32x4*)&RL[px][c0 + 4];
    bf16x8 bxf, brf;
    #pragma unroll
    for (int r = 0; r < 4; ++r) {
        bxf[r]     = (short)f2bf(x0[r]);
        bxf[r + 4] = (short)f2bf(x1[r]);
        brf[r]     = (short)f2bf(r0[r]);
        brf[r + 4] = (short)f2bf(r1[r]);
    }

    const f32x4 cz = {0.f, 0.f, 0.f, 0.f};
    #pragma unroll
    for (int ot = 0; ot < 6; ++ot) {
        bf16x8 wa;
        const float s = (ot == 0) ? L2E : 1.0f;   // fold log2e into Q
        #pragma unroll
        for (int r = 0; r < 8; ++r) wa[r] = (short)f2bf(wf[ot][r] * s);
        const f32x4 acc = MFMA16(wa, (ot == 0 ? brf : bxf), cz);
        #pragma unroll
        for (int r = 0; r < 4; ++r)
            OP[cw][ot * 16 + g * 4 + r][pw * 16 + li] = acc[r];
    }
    __syncthreads();

    {   // Q and K: 32 px x 8 channel-pairs
        const int p = t >> 3, cp = t & 7;
        const float q0 = OP[0][cp * 2][p]     + OP[1][cp * 2][p]     + BLs[cp * 2];
        const float q1 = OP[0][cp * 2 + 1][p] + OP[1][cp * 2 + 1][p] + BLs[cp * 2 + 1];
        *(uint*)&Qo[(size_t)(b * N_ + n0 + p) * 16 + cp * 2] = packbf(q0, q1);
        const float k0 = OP[0][16 + cp * 2][p]     + OP[1][16 + cp * 2][p]     + BLs[16 + cp * 2];
        const float k1 = OP[0][16 + cp * 2 + 1][p] + OP[1][16 + cp * 2 + 1][p] + BLs[16 + cp * 2 + 1];
        *(uint*)&Ko[(size_t)(b * N_ + n0 + p) * 16 + cp * 2] = packbf(k0, k1);
    }
    {   // V -> VT[b][jt][ch][jin]: 64 ch x 4 pixel-octets
        const int ch = t >> 2, po = (t & 3) * 8;
        const float bs = BLs[32 + ch];
        uint4 o;
        #pragma unroll
        for (int e = 0; e < 4; ++e) {
            const float v0 = OP[0][32 + ch][po + 2 * e]     + OP[1][32 + ch][po + 2 * e]     + bs;
            const float v1 = OP[0][32 + ch][po + 2 * e + 1] + OP[1][32 + ch][po + 2 * e + 1] + bs;
            ((uint*)&o)[e] = packbf(v0, v1);
        }
        const size_t jt = (size_t)b * (N_ / 16) + ((n0 + po) >> 4);
        *(uint4*)&Vo[(jt * 64 + ch) * 16 + (po & 8)] = o;
    }
}

// ---------------- flash attention, 32x32 MFMA, zero-LDS main loop ----------
// 512 thr = 8 waves; wave w owns N/8=512 keys (8 iters of 64 = 2 S-tiles).
// K/V fragments: coalesced global from L2 (VT fragment-major). P in-register
// (cvt_pk + permlane32_swap). PV MFMAs interleaved acc0/acc1 (dep distance 2)
// and split around the st1 exp/pack so VALU overlaps the matrix pipe.
#define JG_   8
#define OTP   36
#define SMEM_FL (73728 + 1056 + 1056 + 128)

__global__ __launch_bounds__(512, 4) void flash32(
    const ushort* __restrict__ Qg, const ushort* __restrict__ Kg,
    const ushort* __restrict__ VT, const float* __restrict__ x,
    const float* __restrict__ lam, float* __restrict__ out)
{
    __shared__ __align__(16) char smem[SMEM_FL];
    float*  OT = (float*)smem;                       // [8][64][OTP]
    float*  MC = (float*)(smem + 73728);             // [8][33]
    float*  LC = (float*)(smem + 73728 + 1056);      // [8][33]
    float*  IV = (float*)(smem + 73728 + 2112);      // [32]

    const int t = threadIdx.x, w = t >> 6, lane = t & 63;
    const int l31 = lane & 31, h = lane >> 5;

    // XCD-locality remap: batch b's 128 blocks land on 2 XCDs (K/V L2-local)
    const int wg = blockIdx.x;
    const int b  = (wg & 7) >> 1;
    const int it = ((wg >> 3) << 1) | (wg & 1);
    const int i0 = it * 32;

    const bf16x8 qf = *(const bf16x8*)(Qg + ((size_t)(b * N_ + i0 + l31)) * 16 + h * 8);

    const size_t jbase = (size_t)w * (N_ / JG_);
    const ushort* kp = Kg + ((size_t)(b * N_) + jbase + l31) * 16 + h * 8;
    const ushort* vt = VT + (((size_t)b * (N_ / 16) + jbase / 16) * 64 + l31) * 16 + h * 8;

    f32x16 acc0, acc1, z16;
    #pragma unroll
    for (int i = 0; i < 16; ++i) { acc0[i] = 0.f; acc1[i] = 0.f; z16[i] = 0.f; }
    float m_run = -1e30f, l_loc = 0.f;

    #pragma unroll 1
    for (int it8 = 0; it8 < 8; ++it8) {
        const int j0 = it8 * 64;
        const ushort* vtj = vt + (size_t)(j0 >> 4) * 1024;

        // ---- energy: two 32-key S-tiles (K=16 exact) ----
        const bf16x8 kf0 = *(const bf16x8*)(kp + (size_t)(j0) * 16);
        const bf16x8 kf1 = *(const bf16x8*)(kp + (size_t)(j0 + 32) * 16);
        f32x16 st0 = MFMA32(kf0, qf, z16);
        f32x16 st1 = MFMA32(kf1, qf, z16);

        // ---- online max + defer-rescale (T13) ----
        float m_c = fmaxf(tmax16(st0), tmax16(st1));
        m_c = fmaxf(m_c, __shfl_xor(m_c, 32));
        if (__any(m_c > m_run + 8.f)) {
            const float m_new = fmaxf(m_run, m_c);
            const float sc = exp2f(m_run - m_new);
            l_loc *= sc;
            #pragma unroll
            for (int i = 0; i < 16; ++i) { acc0[i] *= sc; acc1[i] *= sc; }
            m_run = m_new;
        }

        // ---- st0: exp, pack, first 4 PV MFMAs (acc0/acc1 interleaved) ----
        #pragma unroll
        for (int i = 0; i < 16; ++i) st0[i] = exp2f(st0[i] - m_run);
        uint A0 = cvtpk(st0[0],  st0[1]),  A1 = cvtpk(st0[2],  st0[3]);
        uint B0 = cvtpk(st0[4],  st0[5]),  B1 = cvtpk(st0[6],  st0[7]);
        uint C0 = cvtpk(st0[8],  st0[9]),  C1 = cvtpk(st0[10], st0[11]);
        uint D0 = cvtpk(st0[12], st0[13]), D1 = cvtpk(st0[14], st0[15]);
        plswap(A0, B0); plswap(A1, B1); plswap(C0, D0); plswap(C1, D1);
        uint4v u0 = {A0, A1, B0, B1}, u1 = {C0, C1, D0, D1};
        const bf16x8 pf0 = __builtin_bit_cast(bf16x8, u0);
        const bf16x8 pf1 = __builtin_bit_cast(bf16x8, u1);
        const bf16x8 va0 = *(const bf16x8*)(vtj);
        const bf16x8 vb0 = *(const bf16x8*)(vtj + 512);
        const bf16x8 va1 = *(const bf16x8*)(vtj + 1024);
        const bf16x8 vb1 = *(const bf16x8*)(vtj + 1536);
        acc0 = MFMA32(va0, pf0, acc0);
        acc1 = MFMA32(vb0, pf0, acc1);
        acc0 = MFMA32(va1, pf1, acc0);
        acc1 = MFMA32(vb1, pf1, acc1);

        // ---- st1: exp, pack (overlaps matrix pipe), last 4 MFMAs ----
        #pragma unroll
        for (int i = 0; i < 16; ++i) st1[i] = exp2f(st1[i] - m_run);
        uint E0 = cvtpk(st1[0],  st1[1]),  E1 = cvtpk(st1[2],  st1[3]);
        uint F0 = cvtpk(st1[4],  st1[5]),  F1 = cvtpk(st1[6],  st1[7]);
        uint G0 = cvtpk(st1[8],  st1[9]),  G1 = cvtpk(st1[10], st1[11]);
        uint H0 = cvtpk(st1[12], st1[13]), H1 = cvtpk(st1[14], st1[15]);
        plswap(E0, F0); plswap(E1, F1); plswap(G0, H0); plswap(G1, H1);
        uint4v u2 = {E0, E1, F0, F1}, u3 = {G0, G1, H0, H1};
        const bf16x8 pf2 = __builtin_bit_cast(bf16x8, u2);
        const bf16x8 pf3 = __builtin_bit_cast(bf16x8, u3);
        const bf16x8 va2 = *(const bf16x8*)(vtj + 2048);
        const bf16x8 vb2 = *(const bf16x8*)(vtj + 2560);
        const bf16x8 va3 = *(const bf16x8*)(vtj + 3072);
        const bf16x8 vb3 = *(const bf16x8*)(vtj + 3584);
        acc0 = MFMA32(va2, pf2, acc0);
        acc1 = MFMA32(vb2, pf2, acc1);
        acc0 = MFMA32(va3, pf3, acc0);
        acc1 = MFMA32(vb3, pf3, acc1);

        l_loc += tsum16(st0) + tsum16(st1);
    }
    const float l_run = l_loc + __shfl_xor(l_loc, 32);

    // ---- merge 8 j-partials ----
    if (h == 0) { MC[w * 33 + l31] = m_run; LC[w * 33 + l31] = l_run; }
    __syncthreads();                        // bar0

    float mp[8];
    #pragma unroll
    for (int p = 0; p < 8; ++p) mp[p] = MC[p * 33 + l31];
    float ms = mp[0];
    #pragma unroll
    for (int p = 1; p < 8; ++p) ms = fmaxf(ms, mp[p]);
    float lsum = 0.f, wt_own = 0.f;
    #pragma unroll
    for (int p = 0; p < 8; ++p) {
        const float wt = exp2f(mp[p] - ms);
        lsum += wt * LC[p * 33 + l31];
        if (p == w) wt_own = wt;
    }
    if (w == 0 && h == 0) IV[l31] = lam[0] / lsum;

    #pragma unroll
    for (int r = 0; r < 16; ++r) {
        const int c = (r & 3) + 8 * (r >> 2) + 4 * h;
        OT[(w * 64 + c) * OTP + l31]      = acc0[r] * wt_own;
        OT[(w * 64 + c + 32) * OTP + l31] = acc1[r] * wt_own;
    }
    __syncthreads();                        // bar1

    // ---- epilogue: out = sum_p OT[p] * IV + x ----
    {
        const int c = t >> 3, sg = t & 7;
        f32x4 o = {0.f, 0.f, 0.f, 0.f};
        #pragma unroll
        for (int p = 0; p < 8; ++p) {
            const f32x4 v = *(const f32x4*)&OT[(p * 64 + c) * OTP + sg * 4];
            o[0] += v[0]; o[1] += v[1]; o[2] += v[2]; o[3] += v[3];
        }
        const size_t off = ((size_t)b * C_ + c) * N_ + i0 + sg * 4;
        const float4 xv = *(const float4*)(x + off);
        float4 res;
        res.x = o[0] * IV[sg * 4 + 0] + xv.x;
        res.y = o[1] * IV[sg * 4 + 1] + xv.y;
        res.z = o[2] * IV[sg * 4 + 2] + xv.z;
        res.w = o[3] * IV[sg * 4 + 3] + xv.w;
        *(float4*)(out + off) = res;
    }
}

extern "C" void kernel_launch(void* const* d_in, const int* in_sizes, int n_in,
                              void* d_out, int out_size, void* d_ws, size_t ws_size,
                              hipStream_t stream)
{
    (void)in_sizes; (void)n_in; (void)out_size; (void)ws_size;
    const float* x    = (const float*)d_in[0];
    const float* xrgb = (const float*)d_in[1];
    const float* Wq   = (const float*)d_in[2];
    const float* bq   = (const float*)d_in[3];
    const float* Wk   = (const float*)d_in[4];
    const float* bk   = (const float*)d_in[5];
    const float* Wv   = (const float*)d_in[6];
    const float* bv   = (const float*)d_in[7];
    const float* lam  = (const float*)d_in[8];
    float* out = (float*)d_out;

    // workspace (bf16): Q 512KB | K 512KB | VT 2MB — all fully overwritten
    ushort* Qw = (ushort*)d_ws;                       // [B][N][16]
    ushort* Kw = Qw + (size_t)B_ * N_ * 16;           // [B][N][16]
    ushort* Vw = Kw + (size_t)B_ * N_ * 16;           // VT[B][N/16][64][16]

    qkv_mfma<<<dim3(N_ / 32, B_), 256, 0, stream>>>(
        x, xrgb, Wq, bq, Wk, bk, Wv, bv, Qw, Kw, Vw);

    flash32<<<dim3(512), 512, 0, stream>>>(
        Qw, Kw, Vw, x, lam, out);
}